// Round 1
// baseline (463.327 us; speedup 1.0000x reference)
//
#include <hip/hip_runtime.h>
#include <math.h>

// GAT actor-critic forward on MI355X.
// Structure: CSR built per-call (hist + scan + scatter) -> wave-per-node
// softmax-aggregation with register accumulation (no float atomics).

__device__ __forceinline__ float leaky02(float e){ return e > 0.f ? e : 0.2f*e; }

// ---------------- init: zero degree hist, seed value slot with bc ----------------
__global__ void k_init(int* __restrict__ deg, int n, float* __restrict__ out_val,
                       const float* __restrict__ bc)
{
    int i = blockIdx.x*blockDim.x + threadIdx.x;
    if (i < n) deg[i] = 0;
    if (i == 0) *out_val = bc[0];
}

// ---------------- gemm1: h1[N,128] = x[N,128] @ W[128,128]; fused a_s/a_d dots ----------------
__global__ __launch_bounds__(256) void k_gemm1(const float* __restrict__ x, const float* __restrict__ W,
        const float* __restrict__ aS, const float* __restrict__ aD,
        float* __restrict__ h1, float* __restrict__ pAS, float* __restrict__ pAD, int n)
{
    __shared__ float xs[64*32];    // 8 KB   [row][k]
    __shared__ float ws[32*128];   // 16 KB  [k][col]
    const int tid  = threadIdx.x;
    const int brow = blockIdx.x*64;
    const int tc = tid & 31, tr = tid >> 5;
    const int c0 = tc*4, r0 = tr*8;

    float acc[8][4];
    #pragma unroll
    for (int i=0;i<8;i++){ acc[i][0]=0.f; acc[i][1]=0.f; acc[i][2]=0.f; acc[i][3]=0.f; }

    for (int kt=0; kt<4; kt++){
        #pragma unroll
        for (int i=0;i<2;i++){                 // xs: 512 float4s
            int fi = tid*2+i;
            int row = fi>>3, kk = (fi&7)*4;
            float4 v = make_float4(0.f,0.f,0.f,0.f);
            if (brow+row < n) v = *(const float4*)&x[(size_t)(brow+row)*128 + kt*32 + kk];
            *(float4*)&xs[row*32+kk] = v;
        }
        #pragma unroll
        for (int j=0;j<4;j++){                 // ws: 1024 float4s
            int fi = tid + j*256;
            int kr = fi>>5, cc = (fi&31)*4;
            *(float4*)&ws[kr*128+cc] = *(const float4*)&W[(size_t)(kt*32+kr)*128+cc];
        }
        __syncthreads();
        #pragma unroll
        for (int k=0;k<32;k++){
            float4 wv = *(const float4*)&ws[k*128+c0];
            #pragma unroll
            for (int rr=0; rr<8; rr++){
                float xv = xs[(r0+rr)*32+k];
                acc[rr][0] += xv*wv.x; acc[rr][1] += xv*wv.y;
                acc[rr][2] += xv*wv.z; acc[rr][3] += xv*wv.w;
            }
        }
        __syncthreads();
    }

    // epilogue: store h1, and per-(row,head) attention dots reduced over the
    // 8 lanes (tc&7) that cover this head's 32 channels.
    const int hd  = tc >> 3;               // head = c0/32
    const int off = (tc & 7)*4;            // channel offset inside head
    float s0=aS[hd*32+off+0], s1=aS[hd*32+off+1], s2=aS[hd*32+off+2], s3=aS[hd*32+off+3];
    float d0=aD[hd*32+off+0], d1=aD[hd*32+off+1], d2=aD[hd*32+off+2], d3=aD[hd*32+off+3];
    #pragma unroll
    for (int rr=0; rr<8; rr++){
        int row = brow + r0 + rr;
        float ps = acc[rr][0]*s0 + acc[rr][1]*s1 + acc[rr][2]*s2 + acc[rr][3]*s3;
        float pd = acc[rr][0]*d0 + acc[rr][1]*d1 + acc[rr][2]*d2 + acc[rr][3]*d3;
        ps += __shfl_xor(ps,1,64); ps += __shfl_xor(ps,2,64); ps += __shfl_xor(ps,4,64);
        pd += __shfl_xor(pd,1,64); pd += __shfl_xor(pd,2,64); pd += __shfl_xor(pd,4,64);
        if (row < n){
            *(float4*)&h1[(size_t)row*128+c0] = make_float4(acc[rr][0],acc[rr][1],acc[rr][2],acc[rr][3]);
            if ((tc&7)==0){ pAS[row*4+hd] = ps; pAD[row*4+hd] = pd; }
        }
    }
}

// ---------------- histogram of dst degrees (incl self loops) ----------------
__global__ void k_hist(const int* __restrict__ ei, int e, int e2, int* __restrict__ deg)
{
    int g = blockIdx.x*blockDim.x + threadIdx.x;
    if (g < e2){
        int d = (g < e) ? ei[(size_t)e + g] : (g - e);
        atomicAdd(&deg[d], 1);
    }
}

// ---------------- 3-kernel exclusive scan over deg -> row_start/row_end/cursor ----------------
__global__ void k_scan_local(const int* __restrict__ deg, int* __restrict__ tmp,
                             int* __restrict__ blkSum, int n)
{
    __shared__ int sb[256];
    int tid = threadIdx.x;
    int i = blockIdx.x*256 + tid;
    int v = (i < n) ? deg[i] : 0;
    sb[tid] = v; __syncthreads();
    for (int off=1; off<256; off<<=1){
        int t = (tid >= off) ? sb[tid-off] : 0;
        __syncthreads();
        if (tid >= off) sb[tid] += t;
        __syncthreads();
    }
    if (i < n) tmp[i] = sb[tid];           // inclusive local scan
    if (tid == 255) blkSum[blockIdx.x] = sb[255];
}

__global__ void k_scan_blk(const int* __restrict__ bs, int* __restrict__ bo, int nb)
{
    __shared__ int sb[256];
    int tid = threadIdx.x;
    int v = (tid < nb) ? bs[tid] : 0;
    sb[tid] = v; __syncthreads();
    for (int off=1; off<256; off<<=1){
        int t = (tid >= off) ? sb[tid-off] : 0;
        __syncthreads();
        if (tid >= off) sb[tid] += t;
        __syncthreads();
    }
    if (tid < nb) bo[tid] = sb[tid] - v;   // exclusive block offsets
}

__global__ void k_scan_fix(const int* __restrict__ tmp, const int* __restrict__ bo,
                           const int* __restrict__ deg, int* __restrict__ rs,
                           int* __restrict__ re, int* __restrict__ cur, int n)
{
    int i = blockIdx.x*blockDim.x + threadIdx.x;
    if (i < n){
        int G = tmp[i] + bo[i >> 8];       // global inclusive
        int d = deg[i];
        rs[i]  = G - d;
        cur[i] = G - d;
        re[i]  = G;
    }
}

// ---------------- scatter edges into CSR (src lists grouped by dst) ----------------
__global__ void k_scatter(const int* __restrict__ ei, int e, int e2,
                          int* __restrict__ cur, int* __restrict__ csr)
{
    int g = blockIdx.x*blockDim.x + threadIdx.x;
    if (g < e2){
        int s, d;
        if (g < e){ s = ei[g]; d = ei[(size_t)e + g]; }
        else      { s = g - e; d = g - e; }
        int p = atomicAdd(&cur[d], 1);
        csr[p] = s;
    }
}

// ---------------- layer-1 aggregation: wave per node, 2 channels/lane, 4 heads ----------------
__global__ __launch_bounds__(256) void k_agg1(const int* __restrict__ rs, const int* __restrict__ re,
        const int* __restrict__ csr, const float* __restrict__ as1, const float* __restrict__ ad1,
        const float* __restrict__ h1, const float* __restrict__ b1, float* __restrict__ out, int n)
{
    const int lane = threadIdx.x & 63;
    const int node = blockIdx.x*4 + (threadIdx.x >> 6);
    if (node >= n) return;
    const int h = lane >> 4;          // feature f=2*lane -> head = lane/16
    const int f = lane*2;
    const float adv = ad1[node*4 + h];
    const int start = rs[node], end = re[node];

    float m = -1e30f;
    for (int i=start; i<end; i++){
        int s = csr[i];
        float e = leaky02(as1[s*4+h] + adv);
        m = fmaxf(m, e);
    }
    float den = 0.f, ax = 0.f, ay = 0.f;
    for (int i=start; i<end; i++){
        int s = csr[i];
        float e  = leaky02(as1[s*4+h] + adv);
        float ex = __expf(e - m);
        den += ex;
        float2 hv = *(const float2*)&h1[(size_t)s*128 + f];
        ax += ex*hv.x; ay += ex*hv.y;
    }
    float ox = ax/den + b1[f];
    float oy = ay/den + b1[f+1];
    ox = ox > 0.f ? ox : expm1f(ox);
    oy = oy > 0.f ? oy : expm1f(oy);
    *(float2*)&out[(size_t)node*128 + f] = make_float2(ox, oy);
}

// ---------------- gemm2: h2p[N,32] = h1o[N,128] @ W2[128,32]; fused a_s/a_d ----------------
__global__ __launch_bounds__(256) void k_gemm2(const float* __restrict__ hin, const float* __restrict__ W,
        const float* __restrict__ aS, const float* __restrict__ aD,
        float* __restrict__ h2p, float* __restrict__ pAS, float* __restrict__ pAD, int n)
{
    __shared__ float xs[64*132];   // padded stride 132 to break bank conflicts
    __shared__ float ws[128*32];
    const int tid  = threadIdx.x;
    const int brow = blockIdx.x*64;

    #pragma unroll
    for (int j=0;j<4;j++){                     // ws: 1024 float4s
        int fi = tid + j*256;
        int kr = fi>>3, cc = (fi&7)*4;
        *(float4*)&ws[kr*32+cc] = *(const float4*)&W[(size_t)kr*32+cc];
    }
    #pragma unroll
    for (int j=0;j<8;j++){                     // xs: 2048 float4s
        int fi = tid + j*256;
        int row = fi>>5, cc = (fi&31)*4;
        float4 v = make_float4(0.f,0.f,0.f,0.f);
        if (brow+row < n) v = *(const float4*)&hin[(size_t)(brow+row)*128+cc];
        *(float4*)&xs[row*132+cc] = v;
    }
    __syncthreads();

    const int tc = tid & 7, tr = tid >> 3;
    const int c0 = tc*4, r0 = tr*2;
    float acc[2][4];
    #pragma unroll
    for (int i=0;i<2;i++){ acc[i][0]=0.f; acc[i][1]=0.f; acc[i][2]=0.f; acc[i][3]=0.f; }

    #pragma unroll 4
    for (int k=0;k<128;k++){
        float4 wv = *(const float4*)&ws[k*32+c0];
        float x0 = xs[r0*132+k];
        float x1 = xs[(r0+1)*132+k];
        acc[0][0]+=x0*wv.x; acc[0][1]+=x0*wv.y; acc[0][2]+=x0*wv.z; acc[0][3]+=x0*wv.w;
        acc[1][0]+=x1*wv.x; acc[1][1]+=x1*wv.y; acc[1][2]+=x1*wv.z; acc[1][3]+=x1*wv.w;
    }

    float s0=aS[c0+0], s1=aS[c0+1], s2=aS[c0+2], s3=aS[c0+3];
    float d0=aD[c0+0], d1=aD[c0+1], d2=aD[c0+2], d3=aD[c0+3];
    #pragma unroll
    for (int rr=0; rr<2; rr++){
        int row = brow + r0 + rr;
        float ps = acc[rr][0]*s0 + acc[rr][1]*s1 + acc[rr][2]*s2 + acc[rr][3]*s3;
        float pd = acc[rr][0]*d0 + acc[rr][1]*d1 + acc[rr][2]*d2 + acc[rr][3]*d3;
        ps += __shfl_xor(ps,1,64); ps += __shfl_xor(ps,2,64); ps += __shfl_xor(ps,4,64);
        pd += __shfl_xor(pd,1,64); pd += __shfl_xor(pd,2,64); pd += __shfl_xor(pd,4,64);
        if (row < n){
            *(float4*)&h2p[(size_t)row*32+c0] = make_float4(acc[rr][0],acc[rr][1],acc[rr][2],acc[rr][3]);
            if ((tid&7)==0){ pAS[row] = ps; pAD[row] = pd; }
        }
    }
}

// ---------------- layer-2 aggregation: wave per node, 1 ch/lane, edges split across halves ----------------
__global__ __launch_bounds__(256) void k_agg2(const int* __restrict__ rs, const int* __restrict__ re,
        const int* __restrict__ csr, const float* __restrict__ as2, const float* __restrict__ ad2,
        const float* __restrict__ h2p, const float* __restrict__ b2, float* __restrict__ out, int n)
{
    const int lane = threadIdx.x & 63;
    const int node = blockIdx.x*4 + (threadIdx.x >> 6);
    if (node >= n) return;
    const int f = lane & 31, half = lane >> 5;
    const float adv = ad2[node];
    const int start = rs[node], end = re[node];

    float m = -1e30f;
    for (int i=start+half; i<end; i+=2){
        float e = leaky02(as2[csr[i]] + adv);
        m = fmaxf(m, e);
    }
    m = fmaxf(m, __shfl_xor(m, 32, 64));

    float den = 0.f, acc = 0.f;
    for (int i=start+half; i<end; i+=2){
        int s = csr[i];
        float e  = leaky02(as2[s] + adv);
        float ex = __expf(e - m);
        den += ex;
        acc += ex * h2p[(size_t)s*32 + f];
    }
    den += __shfl_xor(den, 32, 64);
    acc += __shfl_xor(acc, 32, 64);
    if (half == 0){
        float o = acc/den + b2[f];
        o = o > 0.f ? o : expm1f(o);
        out[(size_t)node*32 + f] = o;
    }
}

// ---------------- heads: logits[A,N] (transposed store) + value mean ----------------
__global__ __launch_bounds__(256) void k_head(const float* __restrict__ h2, const float* __restrict__ Wa,
        const float* __restrict__ ba, const float* __restrict__ Wc, int n, float* __restrict__ out)
{
    __shared__ float WaS[1024];
    __shared__ float baS[32], WcS[32];
    int tid = threadIdx.x;
    *(float4*)&WaS[tid*4] = *(const float4*)&Wa[tid*4];
    if (tid < 32){ baS[tid] = ba[tid]; WcS[tid] = Wc[tid]; }
    __syncthreads();

    int nidx = blockIdx.x*256 + tid;
    bool act = nidx < n;
    float hv[32];
    #pragma unroll
    for (int j=0;j<8;j++){
        float4 v = act ? *(const float4*)&h2[(size_t)nidx*32 + j*4] : make_float4(0.f,0.f,0.f,0.f);
        hv[j*4+0]=v.x; hv[j*4+1]=v.y; hv[j*4+2]=v.z; hv[j*4+3]=v.w;
    }
    #pragma unroll
    for (int a=0;a<32;a++){
        float acc = baS[a];
        #pragma unroll
        for (int c=0;c<32;c++) acc += hv[c]*WaS[c*32+a];
        if (act) out[(size_t)a*n + nidx] = acc;
    }
    float v = 0.f;
    #pragma unroll
    for (int c=0;c<32;c++) v += hv[c]*WcS[c];
    #pragma unroll
    for (int msk=1; msk<64; msk<<=1) v += __shfl_xor(v, msk, 64);
    if ((tid & 63) == 0) atomicAdd(&out[(size_t)32*n], v*(1.0f/n));
}

extern "C" void kernel_launch(void* const* d_in, const int* in_sizes, int n_in,
                              void* d_out, int out_size, void* d_ws, size_t ws_size,
                              hipStream_t stream)
{
    const float* x   = (const float*)d_in[0];
    const int*   ei  = (const int*)d_in[1];
    const float* W1  = (const float*)d_in[2];
    const float* a1s = (const float*)d_in[3];
    const float* a1d = (const float*)d_in[4];
    const float* b1  = (const float*)d_in[5];
    const float* W2  = (const float*)d_in[6];
    const float* a2s = (const float*)d_in[7];
    const float* a2d = (const float*)d_in[8];
    const float* b2  = (const float*)d_in[9];
    const float* Wa  = (const float*)d_in[10];
    const float* ba  = (const float*)d_in[11];
    const float* Wc  = (const float*)d_in[12];
    const float* bc  = (const float*)d_in[13];
    float* out = (float*)d_out;

    const int N  = in_sizes[0] / 128;
    const int E  = in_sizes[1] / 2;
    const int E2 = E + N;

    // workspace layout
    float* fws = (float*)d_ws;
    float* h1  = fws;                         // N*128
    float* as1 = h1  + (size_t)N*128;         // N*4
    float* ad1 = as1 + (size_t)N*4;           // N*4
    float* h1o = ad1 + (size_t)N*4;           // N*128
    float* h2p = h1o + (size_t)N*128;         // N*32
    float* as2 = h2p + (size_t)N*32;          // N
    float* ad2 = as2 + (size_t)N;             // N
    float* h2  = ad2 + (size_t)N;             // N*32
    int* deg    = (int*)(h2 + (size_t)N*32);  // N
    int* tmp    = deg + N;                    // N
    int* blkSum = tmp + N;                    // 256
    int* blkOff = blkSum + 256;               // 256
    int* rs     = blkOff + 256;               // N
    int* re     = rs + N;                     // N
    int* cur    = re + N;                     // N
    int* csr    = cur + N;                    // E2

    const int nbN   = (N + 255) / 256;
    const int nbE   = (E2 + 255) / 256;
    const int nbG   = (N + 63) / 64;
    const int nbAgg = (N + 3) / 4;

    k_init<<<nbN, 256, 0, stream>>>(deg, N, out + (size_t)32*N, bc);
    k_gemm1<<<nbG, 256, 0, stream>>>(x, W1, a1s, a1d, h1, as1, ad1, N);
    k_hist<<<nbE, 256, 0, stream>>>(ei, E, E2, deg);
    k_scan_local<<<nbN, 256, 0, stream>>>(deg, tmp, blkSum, N);
    k_scan_blk<<<1, 256, 0, stream>>>(blkSum, blkOff, nbN);
    k_scan_fix<<<nbN, 256, 0, stream>>>(tmp, blkOff, deg, rs, re, cur, N);
    k_scatter<<<nbE, 256, 0, stream>>>(ei, E, E2, cur, csr);
    k_agg1<<<nbAgg, 256, 0, stream>>>(rs, re, csr, as1, ad1, h1, b1, h1o, N);
    k_gemm2<<<nbG, 256, 0, stream>>>(h1o, W2, a2s, a2d, h2p, as2, ad2, N);
    k_agg2<<<nbAgg, 256, 0, stream>>>(rs, re, csr, as2, ad2, h2p, b2, h2, N);
    k_head<<<nbN, 256, 0, stream>>>(h2, Wa, ba, Wc, N, out);
}

// Round 2
// 356.322 us; speedup vs baseline: 1.3003x; 1.3003x over previous
//
#include <hip/hip_runtime.h>
#include <math.h>

// GAT actor-critic forward on MI355X.
// CSR built per-call (hist + scan + scatter) -> wave-per-node single-pass
// softmax-aggregation (no max subtraction; logits bounded) with bf16 message
// payloads (h1, h2p stored bf16; attention logits + accumulation fp32).

__device__ __forceinline__ float leaky02(float e){ return e > 0.f ? e : 0.2f*e; }

// bf16 helpers (RNE)
__device__ __forceinline__ unsigned short f2bf(float f){
    union { float f; unsigned int i; } v; v.f = f;
    unsigned int r = v.i + 0x7fffu + ((v.i >> 16) & 1u);
    return (unsigned short)(r >> 16);
}
__device__ __forceinline__ float bfx(unsigned int g){   // low bf16 of packed pair
    union { unsigned int i; float f; } v; v.i = g << 16; return v.f;
}
__device__ __forceinline__ float bfy(unsigned int g){   // high bf16
    union { unsigned int i; float f; } v; v.i = g & 0xffff0000u; return v.f;
}
__device__ __forceinline__ float bf1(unsigned short u){
    union { unsigned int i; float f; } v; v.i = ((unsigned int)u) << 16; return v.f;
}

// ---------------- init: zero degree hist, seed value slot with bc ----------------
__global__ void k_init(int* __restrict__ deg, int n, float* __restrict__ out_val,
                       const float* __restrict__ bc)
{
    int i = blockIdx.x*blockDim.x + threadIdx.x;
    if (i < n) deg[i] = 0;
    if (i == 0) *out_val = bc[0];
}

// ---------------- gemm1: h1b[N,128](bf16) = x @ W1; fused a_s/a_d dots ----------------
__global__ __launch_bounds__(256) void k_gemm1(const float* __restrict__ x, const float* __restrict__ W,
        const float* __restrict__ aS, const float* __restrict__ aD,
        unsigned short* __restrict__ h1b, float* __restrict__ pAS, float* __restrict__ pAD, int n)
{
    __shared__ float xs[64*32];    // 8 KB   [row][k]
    __shared__ float ws[32*128];   // 16 KB  [k][col]
    const int tid  = threadIdx.x;
    const int brow = blockIdx.x*64;
    const int tc = tid & 31, tr = tid >> 5;
    const int c0 = tc*4, r0 = tr*8;

    float acc[8][4];
    #pragma unroll
    for (int i=0;i<8;i++){ acc[i][0]=0.f; acc[i][1]=0.f; acc[i][2]=0.f; acc[i][3]=0.f; }

    for (int kt=0; kt<4; kt++){
        #pragma unroll
        for (int i=0;i<2;i++){                 // xs: 512 float4s
            int fi = tid*2+i;
            int row = fi>>3, kk = (fi&7)*4;
            float4 v = make_float4(0.f,0.f,0.f,0.f);
            if (brow+row < n) v = *(const float4*)&x[(size_t)(brow+row)*128 + kt*32 + kk];
            *(float4*)&xs[row*32+kk] = v;
        }
        #pragma unroll
        for (int j=0;j<4;j++){                 // ws: 1024 float4s
            int fi = tid + j*256;
            int kr = fi>>5, cc = (fi&31)*4;
            *(float4*)&ws[kr*128+cc] = *(const float4*)&W[(size_t)(kt*32+kr)*128+cc];
        }
        __syncthreads();
        #pragma unroll
        for (int k=0;k<32;k++){
            float4 wv = *(const float4*)&ws[k*128+c0];
            #pragma unroll
            for (int rr=0; rr<8; rr++){
                float xv = xs[(r0+rr)*32+k];
                acc[rr][0] += xv*wv.x; acc[rr][1] += xv*wv.y;
                acc[rr][2] += xv*wv.z; acc[rr][3] += xv*wv.w;
            }
        }
        __syncthreads();
    }

    const int hd  = tc >> 3;               // head = c0/32
    const int off = (tc & 7)*4;
    float s0=aS[hd*32+off+0], s1=aS[hd*32+off+1], s2=aS[hd*32+off+2], s3=aS[hd*32+off+3];
    float d0=aD[hd*32+off+0], d1=aD[hd*32+off+1], d2=aD[hd*32+off+2], d3=aD[hd*32+off+3];
    #pragma unroll
    for (int rr=0; rr<8; rr++){
        int row = brow + r0 + rr;
        float ps = acc[rr][0]*s0 + acc[rr][1]*s1 + acc[rr][2]*s2 + acc[rr][3]*s3;
        float pd = acc[rr][0]*d0 + acc[rr][1]*d1 + acc[rr][2]*d2 + acc[rr][3]*d3;
        ps += __shfl_xor(ps,1,64); ps += __shfl_xor(ps,2,64); ps += __shfl_xor(ps,4,64);
        pd += __shfl_xor(pd,1,64); pd += __shfl_xor(pd,2,64); pd += __shfl_xor(pd,4,64);
        if (row < n){
            ushort4 hb = make_ushort4(f2bf(acc[rr][0]), f2bf(acc[rr][1]),
                                      f2bf(acc[rr][2]), f2bf(acc[rr][3]));
            *(ushort4*)&h1b[(size_t)row*128+c0] = hb;
            if ((tc&7)==0){ pAS[row*4+hd] = ps; pAD[row*4+hd] = pd; }
        }
    }
}

// ---------------- histogram of dst degrees (incl self loops) ----------------
__global__ void k_hist(const int* __restrict__ ei, int e, int e2, int* __restrict__ deg)
{
    int g = blockIdx.x*blockDim.x + threadIdx.x;
    if (g < e2){
        int d = (g < e) ? ei[(size_t)e + g] : (g - e);
        atomicAdd(&deg[d], 1);
    }
}

// ---------------- 3-kernel exclusive scan over deg -> row_start/row_end/cursor ----------------
__global__ void k_scan_local(const int* __restrict__ deg, int* __restrict__ tmp,
                             int* __restrict__ blkSum, int n)
{
    __shared__ int sb[256];
    int tid = threadIdx.x;
    int i = blockIdx.x*256 + tid;
    int v = (i < n) ? deg[i] : 0;
    sb[tid] = v; __syncthreads();
    for (int off=1; off<256; off<<=1){
        int t = (tid >= off) ? sb[tid-off] : 0;
        __syncthreads();
        if (tid >= off) sb[tid] += t;
        __syncthreads();
    }
    if (i < n) tmp[i] = sb[tid];
    if (tid == 255) blkSum[blockIdx.x] = sb[255];
}

__global__ void k_scan_blk(const int* __restrict__ bs, int* __restrict__ bo, int nb)
{
    __shared__ int sb[256];
    int tid = threadIdx.x;
    int v = (tid < nb) ? bs[tid] : 0;
    sb[tid] = v; __syncthreads();
    for (int off=1; off<256; off<<=1){
        int t = (tid >= off) ? sb[tid-off] : 0;
        __syncthreads();
        if (tid >= off) sb[tid] += t;
        __syncthreads();
    }
    if (tid < nb) bo[tid] = sb[tid] - v;
}

__global__ void k_scan_fix(const int* __restrict__ tmp, const int* __restrict__ bo,
                           const int* __restrict__ deg, int* __restrict__ rs,
                           int* __restrict__ re, int* __restrict__ cur, int n)
{
    int i = blockIdx.x*blockDim.x + threadIdx.x;
    if (i < n){
        int G = tmp[i] + bo[i >> 8];
        int d = deg[i];
        rs[i]  = G - d;
        cur[i] = G - d;
        re[i]  = G;
    }
}

// ---------------- scatter edges into CSR (src lists grouped by dst) ----------------
__global__ void k_scatter(const int* __restrict__ ei, int e, int e2,
                          int* __restrict__ cur, int* __restrict__ csr)
{
    int g = blockIdx.x*blockDim.x + threadIdx.x;
    if (g < e2){
        int s, d;
        if (g < e){ s = ei[g]; d = ei[(size_t)e + g]; }
        else      { s = g - e; d = g - e; }
        int p = atomicAdd(&cur[d], 1);
        csr[p] = s;
    }
}

// ---------------- layer-1 aggregation: single pass, wave/node, 2 ch/lane ----------------
__global__ __launch_bounds__(256) void k_agg1(const int* __restrict__ rs, const int* __restrict__ re,
        const int* __restrict__ csr, const float* __restrict__ as1, const float* __restrict__ ad1,
        const unsigned short* __restrict__ h1b, const float* __restrict__ b1,
        float* __restrict__ out, int n)
{
    const int lane = threadIdx.x & 63;
    const int node = blockIdx.x*4 + (threadIdx.x >> 6);
    if (node >= n) return;
    const int h = lane >> 4;          // head = (2*lane)/32
    const int f = lane*2;             // feature pair base
    const float adv = ad1[node*4 + h];
    const int start = rs[node], end = re[node];

    float den = 0.f, ax = 0.f, ay = 0.f;
    int i = start;
    for (; i+1 < end; i += 2){        // two independent load chains per iter
        int sA = csr[i], sB = csr[i+1];
        float aA = as1[sA*4+h], aB = as1[sB*4+h];
        unsigned int gA = *(const unsigned int*)&h1b[(size_t)sA*128 + f];
        unsigned int gB = *(const unsigned int*)&h1b[(size_t)sB*128 + f];
        float eA = __expf(leaky02(aA + adv));
        float eB = __expf(leaky02(aB + adv));
        den += eA + eB;
        ax  += eA*bfx(gA) + eB*bfx(gB);
        ay  += eA*bfy(gA) + eB*bfy(gB);
    }
    if (i < end){
        int s = csr[i];
        float e = __expf(leaky02(as1[s*4+h] + adv));
        unsigned int g = *(const unsigned int*)&h1b[(size_t)s*128 + f];
        den += e; ax += e*bfx(g); ay += e*bfy(g);
    }
    float ox = ax/den + b1[f];
    float oy = ay/den + b1[f+1];
    ox = ox > 0.f ? ox : expm1f(ox);
    oy = oy > 0.f ? oy : expm1f(oy);
    *(float2*)&out[(size_t)node*128 + f] = make_float2(ox, oy);
}

// ---------------- gemm2: h2pb[N,32](bf16) = h1o @ W2; fused a_s/a_d ----------------
__global__ __launch_bounds__(256) void k_gemm2(const float* __restrict__ hin, const float* __restrict__ W,
        const float* __restrict__ aS, const float* __restrict__ aD,
        unsigned short* __restrict__ h2pb, float* __restrict__ pAS, float* __restrict__ pAD, int n)
{
    __shared__ float xs[64*132];
    __shared__ float ws[128*32];
    const int tid  = threadIdx.x;
    const int brow = blockIdx.x*64;

    #pragma unroll
    for (int j=0;j<4;j++){
        int fi = tid + j*256;
        int kr = fi>>3, cc = (fi&7)*4;
        *(float4*)&ws[kr*32+cc] = *(const float4*)&W[(size_t)kr*32+cc];
    }
    #pragma unroll
    for (int j=0;j<8;j++){
        int fi = tid + j*256;
        int row = fi>>5, cc = (fi&31)*4;
        float4 v = make_float4(0.f,0.f,0.f,0.f);
        if (brow+row < n) v = *(const float4*)&hin[(size_t)(brow+row)*128+cc];
        *(float4*)&xs[row*132+cc] = v;
    }
    __syncthreads();

    const int tc = tid & 7, tr = tid >> 3;
    const int c0 = tc*4, r0 = tr*2;
    float acc[2][4];
    #pragma unroll
    for (int i=0;i<2;i++){ acc[i][0]=0.f; acc[i][1]=0.f; acc[i][2]=0.f; acc[i][3]=0.f; }

    #pragma unroll 4
    for (int k=0;k<128;k++){
        float4 wv = *(const float4*)&ws[k*32+c0];
        float x0 = xs[r0*132+k];
        float x1 = xs[(r0+1)*132+k];
        acc[0][0]+=x0*wv.x; acc[0][1]+=x0*wv.y; acc[0][2]+=x0*wv.z; acc[0][3]+=x0*wv.w;
        acc[1][0]+=x1*wv.x; acc[1][1]+=x1*wv.y; acc[1][2]+=x1*wv.z; acc[1][3]+=x1*wv.w;
    }

    float s0=aS[c0+0], s1=aS[c0+1], s2=aS[c0+2], s3=aS[c0+3];
    float d0=aD[c0+0], d1=aD[c0+1], d2=aD[c0+2], d3=aD[c0+3];
    #pragma unroll
    for (int rr=0; rr<2; rr++){
        int row = brow + r0 + rr;
        float ps = acc[rr][0]*s0 + acc[rr][1]*s1 + acc[rr][2]*s2 + acc[rr][3]*s3;
        float pd = acc[rr][0]*d0 + acc[rr][1]*d1 + acc[rr][2]*d2 + acc[rr][3]*d3;
        ps += __shfl_xor(ps,1,64); ps += __shfl_xor(ps,2,64); ps += __shfl_xor(ps,4,64);
        pd += __shfl_xor(pd,1,64); pd += __shfl_xor(pd,2,64); pd += __shfl_xor(pd,4,64);
        if (row < n){
            ushort4 hb = make_ushort4(f2bf(acc[rr][0]), f2bf(acc[rr][1]),
                                      f2bf(acc[rr][2]), f2bf(acc[rr][3]));
            *(ushort4*)&h2pb[(size_t)row*32+c0] = hb;
            if ((tid&7)==0){ pAS[row] = ps; pAD[row] = pd; }
        }
    }
}

// ---------------- layer-2 aggregation: single pass, wave/node, edges split across halves ----------------
__global__ __launch_bounds__(256) void k_agg2(const int* __restrict__ rs, const int* __restrict__ re,
        const int* __restrict__ csr, const float* __restrict__ as2, const float* __restrict__ ad2,
        const unsigned short* __restrict__ h2pb, const float* __restrict__ b2,
        float* __restrict__ out, int n)
{
    const int lane = threadIdx.x & 63;
    const int node = blockIdx.x*4 + (threadIdx.x >> 6);
    if (node >= n) return;
    const int f = lane & 31, half = lane >> 5;
    const float adv = ad2[node];
    const int start = rs[node], end = re[node];

    float den = 0.f, acc = 0.f;
    int i = start + half;
    for (; i+2 < end; i += 4){        // unroll-by-2 within this half
        int sA = csr[i], sB = csr[i+2];
        float aA = as2[sA], aB = as2[sB];
        float hA = bf1(h2pb[(size_t)sA*32 + f]);
        float hB = bf1(h2pb[(size_t)sB*32 + f]);
        float eA = __expf(leaky02(aA + adv));
        float eB = __expf(leaky02(aB + adv));
        den += eA + eB;
        acc += eA*hA + eB*hB;
    }
    if (i < end){
        int s = csr[i];
        float e = __expf(leaky02(as2[s] + adv));
        den += e;
        acc += e * bf1(h2pb[(size_t)s*32 + f]);
    }
    den += __shfl_xor(den, 32, 64);
    acc += __shfl_xor(acc, 32, 64);
    if (half == 0){
        float o = acc/den + b2[f];
        o = o > 0.f ? o : expm1f(o);
        out[(size_t)node*32 + f] = o;
    }
}

// ---------------- heads: logits[A,N] (transposed store) + value mean ----------------
__global__ __launch_bounds__(256) void k_head(const float* __restrict__ h2, const float* __restrict__ Wa,
        const float* __restrict__ ba, const float* __restrict__ Wc, int n, float* __restrict__ out)
{
    __shared__ float WaS[1024];
    __shared__ float baS[32], WcS[32];
    int tid = threadIdx.x;
    *(float4*)&WaS[tid*4] = *(const float4*)&Wa[tid*4];
    if (tid < 32){ baS[tid] = ba[tid]; WcS[tid] = Wc[tid]; }
    __syncthreads();

    int nidx = blockIdx.x*256 + tid;
    bool act = nidx < n;
    float hv[32];
    #pragma unroll
    for (int j=0;j<8;j++){
        float4 v = act ? *(const float4*)&h2[(size_t)nidx*32 + j*4] : make_float4(0.f,0.f,0.f,0.f);
        hv[j*4+0]=v.x; hv[j*4+1]=v.y; hv[j*4+2]=v.z; hv[j*4+3]=v.w;
    }
    #pragma unroll
    for (int a=0;a<32;a++){
        float acc = baS[a];
        #pragma unroll
        for (int c=0;c<32;c++) acc += hv[c]*WaS[c*32+a];
        if (act) out[(size_t)a*n + nidx] = acc;
    }
    float v = 0.f;
    #pragma unroll
    for (int c=0;c<32;c++) v += hv[c]*WcS[c];
    #pragma unroll
    for (int msk=1; msk<64; msk<<=1) v += __shfl_xor(v, msk, 64);
    if ((tid & 63) == 0) atomicAdd(&out[(size_t)32*n], v*(1.0f/n));
}

extern "C" void kernel_launch(void* const* d_in, const int* in_sizes, int n_in,
                              void* d_out, int out_size, void* d_ws, size_t ws_size,
                              hipStream_t stream)
{
    const float* x   = (const float*)d_in[0];
    const int*   ei  = (const int*)d_in[1];
    const float* W1  = (const float*)d_in[2];
    const float* a1s = (const float*)d_in[3];
    const float* a1d = (const float*)d_in[4];
    const float* b1  = (const float*)d_in[5];
    const float* W2  = (const float*)d_in[6];
    const float* a2s = (const float*)d_in[7];
    const float* a2d = (const float*)d_in[8];
    const float* b2  = (const float*)d_in[9];
    const float* Wa  = (const float*)d_in[10];
    const float* ba  = (const float*)d_in[11];
    const float* Wc  = (const float*)d_in[12];
    const float* bc  = (const float*)d_in[13];
    float* out = (float*)d_out;

    const int N  = in_sizes[0] / 128;
    const int E  = in_sizes[1] / 2;
    const int E2 = E + N;

    // workspace layout (256B-aligned chunks)
    char* base = (char*)d_ws;
    auto alloc = [&](size_t bytes) -> char* {
        char* p = base; base += (bytes + 255) & ~(size_t)255; return p;
    };
    float* h1o  = (float*)alloc((size_t)N*128*4);
    float* h2   = (float*)alloc((size_t)N*32*4);
    float* as1  = (float*)alloc((size_t)N*4*4);
    float* ad1  = (float*)alloc((size_t)N*4*4);
    float* as2  = (float*)alloc((size_t)N*4);
    float* ad2  = (float*)alloc((size_t)N*4);
    int* deg    = (int*)alloc((size_t)N*4);
    int* tmp    = (int*)alloc((size_t)N*4);
    int* blkSum = (int*)alloc(1024);
    int* blkOff = (int*)alloc(1024);
    int* rs     = (int*)alloc((size_t)N*4);
    int* re     = (int*)alloc((size_t)N*4);
    int* cur    = (int*)alloc((size_t)N*4);
    int* csr    = (int*)alloc((size_t)E2*4);
    unsigned short* h1b  = (unsigned short*)alloc((size_t)N*128*2);
    unsigned short* h2pb = (unsigned short*)alloc((size_t)N*32*2);

    const int nbN   = (N + 255) / 256;
    const int nbE   = (E2 + 255) / 256;
    const int nbG   = (N + 63) / 64;
    const int nbAgg = (N + 3) / 4;

    k_init<<<nbN, 256, 0, stream>>>(deg, N, out + (size_t)32*N, bc);
    k_gemm1<<<nbG, 256, 0, stream>>>(x, W1, a1s, a1d, h1b, as1, ad1, N);
    k_hist<<<nbE, 256, 0, stream>>>(ei, E, E2, deg);
    k_scan_local<<<nbN, 256, 0, stream>>>(deg, tmp, blkSum, N);
    k_scan_blk<<<1, 256, 0, stream>>>(blkSum, blkOff, nbN);
    k_scan_fix<<<nbN, 256, 0, stream>>>(tmp, blkOff, deg, rs, re, cur, N);
    k_scatter<<<nbE, 256, 0, stream>>>(ei, E, E2, cur, csr);
    k_agg1<<<nbAgg, 256, 0, stream>>>(rs, re, csr, as1, ad1, h1b, b1, h1o, N);
    k_gemm2<<<nbG, 256, 0, stream>>>(h1o, W2, a2s, a2d, h2pb, as2, ad2, N);
    k_agg2<<<nbAgg, 256, 0, stream>>>(rs, re, csr, as2, ad2, h2pb, b2, h2, N);
    k_head<<<nbN, 256, 0, stream>>>(h2, Wa, ba, Wc, N, out);
}

// Round 3
// 317.457 us; speedup vs baseline: 1.4595x; 1.1224x over previous
//
#include <hip/hip_runtime.h>
#include <math.h>

// GAT actor-critic forward on MI355X.
// CSR built per-call (hist fused into gemm1 + scan + scatter) -> wave-per-node
// chunk-16 softmax-aggregation: lane j computes edge j's exp once, payload
// gathers issued 16-deep for MLP. bf16 message payloads, fp32 accumulation.

__device__ __forceinline__ float leaky02(float e){ return e > 0.f ? e : 0.2f*e; }

// bf16 helpers (RNE)
__device__ __forceinline__ unsigned short f2bf(float f){
    union { float f; unsigned int i; } v; v.f = f;
    unsigned int r = v.i + 0x7fffu + ((v.i >> 16) & 1u);
    return (unsigned short)(r >> 16);
}
__device__ __forceinline__ float bfx(unsigned int g){
    union { unsigned int i; float f; } v; v.i = g << 16; return v.f;
}
__device__ __forceinline__ float bfy(unsigned int g){
    union { unsigned int i; float f; } v; v.i = g & 0xffff0000u; return v.f;
}
__device__ __forceinline__ float bf1(unsigned short u){
    union { unsigned int i; float f; } v; v.i = ((unsigned int)u) << 16; return v.f;
}

// ---------------- gemm1 (+ fused dst-degree histogram): h1b[N,128](bf16) = x @ W1 ----------------
__global__ __launch_bounds__(256) void k_gemm1(const float* __restrict__ x, const float* __restrict__ W,
        const float* __restrict__ aS, const float* __restrict__ aD,
        unsigned short* __restrict__ h1b, float* __restrict__ pAS, float* __restrict__ pAD, int n,
        const int* __restrict__ ei, int e, int e2, int* __restrict__ deg)
{
    __shared__ float xs[64*32];    // 8 KB   [row][k]
    __shared__ float ws[32*128];   // 16 KB  [k][col]
    const int tid  = threadIdx.x;
    const int brow = blockIdx.x*64;

    // fused histogram: fire-and-forget atomics, hidden under the GEMM compute
    {
        int g = blockIdx.x*256 + tid;
        int stride = gridDim.x*256;
        for (; g < e2; g += stride){
            int d = (g < e) ? ei[(size_t)e + g] : (g - e);
            atomicAdd(&deg[d], 1);
        }
    }

    const int tc = tid & 31, tr = tid >> 5;
    const int c0 = tc*4, r0 = tr*8;

    float acc[8][4];
    #pragma unroll
    for (int i=0;i<8;i++){ acc[i][0]=0.f; acc[i][1]=0.f; acc[i][2]=0.f; acc[i][3]=0.f; }

    for (int kt=0; kt<4; kt++){
        #pragma unroll
        for (int i=0;i<2;i++){
            int fi = tid*2+i;
            int row = fi>>3, kk = (fi&7)*4;
            float4 v = make_float4(0.f,0.f,0.f,0.f);
            if (brow+row < n) v = *(const float4*)&x[(size_t)(brow+row)*128 + kt*32 + kk];
            *(float4*)&xs[row*32+kk] = v;
        }
        #pragma unroll
        for (int j=0;j<4;j++){
            int fi = tid + j*256;
            int kr = fi>>5, cc = (fi&31)*4;
            *(float4*)&ws[kr*128+cc] = *(const float4*)&W[(size_t)(kt*32+kr)*128+cc];
        }
        __syncthreads();
        #pragma unroll
        for (int k=0;k<32;k++){
            float4 wv = *(const float4*)&ws[k*128+c0];
            #pragma unroll
            for (int rr=0; rr<8; rr++){
                float xv = xs[(r0+rr)*32+k];
                acc[rr][0] += xv*wv.x; acc[rr][1] += xv*wv.y;
                acc[rr][2] += xv*wv.z; acc[rr][3] += xv*wv.w;
            }
        }
        __syncthreads();
    }

    const int hd  = tc >> 3;
    const int off = (tc & 7)*4;
    float s0=aS[hd*32+off+0], s1=aS[hd*32+off+1], s2=aS[hd*32+off+2], s3=aS[hd*32+off+3];
    float d0=aD[hd*32+off+0], d1=aD[hd*32+off+1], d2=aD[hd*32+off+2], d3=aD[hd*32+off+3];
    #pragma unroll
    for (int rr=0; rr<8; rr++){
        int row = brow + r0 + rr;
        float ps = acc[rr][0]*s0 + acc[rr][1]*s1 + acc[rr][2]*s2 + acc[rr][3]*s3;
        float pd = acc[rr][0]*d0 + acc[rr][1]*d1 + acc[rr][2]*d2 + acc[rr][3]*d3;
        ps += __shfl_xor(ps,1,64); ps += __shfl_xor(ps,2,64); ps += __shfl_xor(ps,4,64);
        pd += __shfl_xor(pd,1,64); pd += __shfl_xor(pd,2,64); pd += __shfl_xor(pd,4,64);
        if (row < n){
            ushort4 hb = make_ushort4(f2bf(acc[rr][0]), f2bf(acc[rr][1]),
                                      f2bf(acc[rr][2]), f2bf(acc[rr][3]));
            *(ushort4*)&h1b[(size_t)row*128+c0] = hb;
            if ((tc&7)==0){ pAS[row*4+hd] = ps; pAD[row*4+hd] = pd; }
        }
    }
}

// ---------------- 3-kernel exclusive scan over deg -> row_start/row_end/cursor ----------------
__global__ void k_scan_local(const int* __restrict__ deg, int* __restrict__ tmp,
                             int* __restrict__ blkSum, int n)
{
    __shared__ int sb[256];
    int tid = threadIdx.x;
    int i = blockIdx.x*256 + tid;
    int v = (i < n) ? deg[i] : 0;
    sb[tid] = v; __syncthreads();
    for (int off=1; off<256; off<<=1){
        int t = (tid >= off) ? sb[tid-off] : 0;
        __syncthreads();
        if (tid >= off) sb[tid] += t;
        __syncthreads();
    }
    if (i < n) tmp[i] = sb[tid];
    if (tid == 255) blkSum[blockIdx.x] = sb[255];
}

__global__ void k_scan_blk(const int* __restrict__ bs, int* __restrict__ bo, int nb,
                           float* __restrict__ out_val, const float* __restrict__ bc)
{
    __shared__ int sb[256];
    int tid = threadIdx.x;
    if (tid == 0) *out_val = bc[0];     // seed value-head bias (out re-poisoned every call)
    int v = (tid < nb) ? bs[tid] : 0;
    sb[tid] = v; __syncthreads();
    for (int off=1; off<256; off<<=1){
        int t = (tid >= off) ? sb[tid-off] : 0;
        __syncthreads();
        if (tid >= off) sb[tid] += t;
        __syncthreads();
    }
    if (tid < nb) bo[tid] = sb[tid] - v;
}

__global__ void k_scan_fix(const int* __restrict__ tmp, const int* __restrict__ bo,
                           const int* __restrict__ deg, int* __restrict__ rs,
                           int* __restrict__ re, int* __restrict__ cur, int n)
{
    int i = blockIdx.x*blockDim.x + threadIdx.x;
    if (i < n){
        int G = tmp[i] + bo[i >> 8];
        int d = deg[i];
        rs[i]  = G - d;
        cur[i] = G - d;
        re[i]  = G;
    }
}

// ---------------- scatter edges into CSR (src lists grouped by dst) ----------------
__global__ void k_scatter(const int* __restrict__ ei, int e, int e2,
                          int* __restrict__ cur, int* __restrict__ csr)
{
    int g = blockIdx.x*blockDim.x + threadIdx.x;
    if (g < e2){
        int s, d;
        if (g < e){ s = ei[g]; d = ei[(size_t)e + g]; }
        else      { s = g - e; d = g - e; }
        int p = atomicAdd(&cur[d], 1);
        csr[p] = s;
    }
}

// ---------------- layer-1 aggregation: chunk-16, lane-parallel exp, 16-deep gather ----------------
__global__ __launch_bounds__(256) void k_agg1(const int* __restrict__ rs, const int* __restrict__ re,
        const int* __restrict__ csr, const float* __restrict__ as1, const float* __restrict__ ad1,
        const unsigned short* __restrict__ h1b, const float* __restrict__ b1,
        float* __restrict__ out, int n)
{
    const int lane = threadIdx.x & 63;
    const int node = blockIdx.x*4 + (threadIdx.x >> 6);
    if (node >= n) return;
    const int h   = lane >> 4;           // head for this lane's channels
    const int f   = lane*2;              // channel pair base
    const int j16 = lane & 15;
    const int grp = lane & 48;
    const float adv = ad1[node*4 + h];
    const int start = rs[node], end = re[node];
    const unsigned int* hp = (const unsigned int*)h1b + (f >> 1);  // index s*64

    float den = 0.f, ax = 0.f, ay = 0.f;
    int i0 = start;

    // full 16-edge chunks
    for (; i0 + 16 <= end; i0 += 16){
        int sj = csr[i0 + j16];
        float e = __expf(leaky02(as1[sj*4 + h] + adv));
        den += e;
        #pragma unroll
        for (int j = 0; j < 16; j++){
            float ej = __shfl(e,  grp + j, 64);
            int   s2 = __shfl(sj, grp + j, 64);
            unsigned int g = hp[s2*64];
            ax += ej*bfx(g); ay += ej*bfy(g);
        }
    }
    // remainder chunk (c < 16), masked unroll-by-4
    int c = end - i0;
    if (c > 0){
        int jj = (j16 < c) ? j16 : (c-1);
        int sj = csr[i0 + jj];
        float e = __expf(leaky02(as1[sj*4 + h] + adv));
        if (j16 < c) den += e;
        for (int j = 0; j < c; j += 4){
            #pragma unroll
            for (int u = 0; u < 4; u++){
                int je = j + u;
                int jc = (je < c) ? je : (c-1);
                float ej = __shfl(e,  grp + jc, 64);
                int   s2 = __shfl(sj, grp + jc, 64);
                ej = (je < c) ? ej : 0.f;
                unsigned int g = hp[s2*64];
                ax += ej*bfx(g); ay += ej*bfy(g);
            }
        }
    }
    // den: reduce over the 16-lane head group (butterfly -> all lanes get total)
    den += __shfl_xor(den, 1, 64);
    den += __shfl_xor(den, 2, 64);
    den += __shfl_xor(den, 4, 64);
    den += __shfl_xor(den, 8, 64);

    float ox = ax/den + b1[f];
    float oy = ay/den + b1[f+1];
    ox = ox > 0.f ? ox : expm1f(ox);
    oy = oy > 0.f ? oy : expm1f(oy);
    *(float2*)&out[(size_t)node*128 + f] = make_float2(ox, oy);
}

// ---------------- gemm2: h2pb[N,32](bf16) = h1o @ W2; fused a_s/a_d ----------------
__global__ __launch_bounds__(256) void k_gemm2(const float* __restrict__ hin, const float* __restrict__ W,
        const float* __restrict__ aS, const float* __restrict__ aD,
        unsigned short* __restrict__ h2pb, float* __restrict__ pAS, float* __restrict__ pAD, int n)
{
    __shared__ float xs[64*132];
    __shared__ float ws[128*32];
    const int tid  = threadIdx.x;
    const int brow = blockIdx.x*64;

    #pragma unroll
    for (int j=0;j<4;j++){
        int fi = tid + j*256;
        int kr = fi>>3, cc = (fi&7)*4;
        *(float4*)&ws[kr*32+cc] = *(const float4*)&W[(size_t)kr*32+cc];
    }
    #pragma unroll
    for (int j=0;j<8;j++){
        int fi = tid + j*256;
        int row = fi>>5, cc = (fi&31)*4;
        float4 v = make_float4(0.f,0.f,0.f,0.f);
        if (brow+row < n) v = *(const float4*)&hin[(size_t)(brow+row)*128+cc];
        *(float4*)&xs[row*132+cc] = v;
    }
    __syncthreads();

    const int tc = tid & 7, tr = tid >> 3;
    const int c0 = tc*4, r0 = tr*2;
    float acc[2][4];
    #pragma unroll
    for (int i=0;i<2;i++){ acc[i][0]=0.f; acc[i][1]=0.f; acc[i][2]=0.f; acc[i][3]=0.f; }

    #pragma unroll 4
    for (int k=0;k<128;k++){
        float4 wv = *(const float4*)&ws[k*32+c0];
        float x0 = xs[r0*132+k];
        float x1 = xs[(r0+1)*132+k];
        acc[0][0]+=x0*wv.x; acc[0][1]+=x0*wv.y; acc[0][2]+=x0*wv.z; acc[0][3]+=x0*wv.w;
        acc[1][0]+=x1*wv.x; acc[1][1]+=x1*wv.y; acc[1][2]+=x1*wv.z; acc[1][3]+=x1*wv.w;
    }

    float s0=aS[c0+0], s1=aS[c0+1], s2=aS[c0+2], s3=aS[c0+3];
    float d0=aD[c0+0], d1=aD[c0+1], d2=aD[c0+2], d3=aD[c0+3];
    #pragma unroll
    for (int rr=0; rr<2; rr++){
        int row = brow + r0 + rr;
        float ps = acc[rr][0]*s0 + acc[rr][1]*s1 + acc[rr][2]*s2 + acc[rr][3]*s3;
        float pd = acc[rr][0]*d0 + acc[rr][1]*d1 + acc[rr][2]*d2 + acc[rr][3]*d3;
        ps += __shfl_xor(ps,1,64); ps += __shfl_xor(ps,2,64); ps += __shfl_xor(ps,4,64);
        pd += __shfl_xor(pd,1,64); pd += __shfl_xor(pd,2,64); pd += __shfl_xor(pd,4,64);
        if (row < n){
            ushort4 hb = make_ushort4(f2bf(acc[rr][0]), f2bf(acc[rr][1]),
                                      f2bf(acc[rr][2]), f2bf(acc[rr][3]));
            *(ushort4*)&h2pb[(size_t)row*32+c0] = hb;
            if ((tid&7)==0){ pAS[row] = ps; pAD[row] = pd; }
        }
    }
}

// ---------------- layer-2 aggregation: chunk-16, halves split payload edges ----------------
__global__ __launch_bounds__(256) void k_agg2(const int* __restrict__ rs, const int* __restrict__ re,
        const int* __restrict__ csr, const float* __restrict__ as2, const float* __restrict__ ad2,
        const unsigned short* __restrict__ h2pb, const float* __restrict__ b2,
        float* __restrict__ out, int n)
{
    const int lane = threadIdx.x & 63;
    const int node = blockIdx.x*4 + (threadIdx.x >> 6);
    if (node >= n) return;
    const int f    = lane & 31;
    const int half = lane >> 5;
    const int j16  = lane & 15;
    const int grp  = lane & 48;
    const float adv = ad2[node];
    const int start = rs[node], end = re[node];
    const unsigned short* hp = h2pb + f;     // index s*32

    float den = 0.f, acc = 0.f;
    int i0 = start;

    for (; i0 + 16 <= end; i0 += 16){
        int sj = csr[i0 + j16];
        float e = __expf(leaky02(as2[sj] + adv));
        den += e;                 // every 16-group holds identical partials
        #pragma unroll
        for (int jj = 0; jj < 8; jj++){
            int j = 2*jj + half;  // this half's edges within the chunk
            float ej = __shfl(e,  grp + j, 64);
            int   s2 = __shfl(sj, grp + j, 64);
            acc += ej * bf1(hp[s2*32]);
        }
    }
    int c = end - i0;
    if (c > 0){
        int jj = (j16 < c) ? j16 : (c-1);
        int sj = csr[i0 + jj];
        float e = __expf(leaky02(as2[sj] + adv));
        if (j16 < c) den += e;
        for (int j = half; j < c; j += 8){
            #pragma unroll
            for (int u = 0; u < 4; u++){
                int je = j + 2*u;
                int jc = (je < c) ? je : (c-1);
                float ej = __shfl(e,  grp + (jc & 15), 64);
                int   s2 = __shfl(sj, grp + (jc & 15), 64);
                ej = (je < c) ? ej : 0.f;
                acc += ej * bf1(hp[s2*32]);
            }
        }
    }
    // den: reduce within 16-lane group -> every lane has total
    den += __shfl_xor(den, 1, 64);
    den += __shfl_xor(den, 2, 64);
    den += __shfl_xor(den, 4, 64);
    den += __shfl_xor(den, 8, 64);
    // acc: combine the two halves of each channel
    acc += __shfl_xor(acc, 32, 64);

    if (half == 0){
        float o = acc/den + b2[f];
        o = o > 0.f ? o : expm1f(o);
        out[(size_t)node*32 + f] = o;
    }
}

// ---------------- heads: logits[A,N] (transposed store) + value mean ----------------
__global__ __launch_bounds__(256) void k_head(const float* __restrict__ h2, const float* __restrict__ Wa,
        const float* __restrict__ ba, const float* __restrict__ Wc, int n, float* __restrict__ out)
{
    __shared__ float WaS[1024];
    __shared__ float baS[32], WcS[32];
    int tid = threadIdx.x;
    *(float4*)&WaS[tid*4] = *(const float4*)&Wa[tid*4];
    if (tid < 32){ baS[tid] = ba[tid]; WcS[tid] = Wc[tid]; }
    __syncthreads();

    int nidx = blockIdx.x*256 + tid;
    bool act = nidx < n;
    float hv[32];
    #pragma unroll
    for (int j=0;j<8;j++){
        float4 v = act ? *(const float4*)&h2[(size_t)nidx*32 + j*4] : make_float4(0.f,0.f,0.f,0.f);
        hv[j*4+0]=v.x; hv[j*4+1]=v.y; hv[j*4+2]=v.z; hv[j*4+3]=v.w;
    }
    #pragma unroll
    for (int a=0;a<32;a++){
        float acc = baS[a];
        #pragma unroll
        for (int c=0;c<32;c++) acc += hv[c]*WaS[c*32+a];
        if (act) out[(size_t)a*n + nidx] = acc;
    }
    float v = 0.f;
    #pragma unroll
    for (int c=0;c<32;c++) v += hv[c]*WcS[c];
    #pragma unroll
    for (int msk=1; msk<64; msk<<=1) v += __shfl_xor(v, msk, 64);
    if ((tid & 63) == 0) atomicAdd(&out[(size_t)32*n], v*(1.0f/n));
}

extern "C" void kernel_launch(void* const* d_in, const int* in_sizes, int n_in,
                              void* d_out, int out_size, void* d_ws, size_t ws_size,
                              hipStream_t stream)
{
    const float* x   = (const float*)d_in[0];
    const int*   ei  = (const int*)d_in[1];
    const float* W1  = (const float*)d_in[2];
    const float* a1s = (const float*)d_in[3];
    const float* a1d = (const float*)d_in[4];
    const float* b1  = (const float*)d_in[5];
    const float* W2  = (const float*)d_in[6];
    const float* a2s = (const float*)d_in[7];
    const float* a2d = (const float*)d_in[8];
    const float* b2  = (const float*)d_in[9];
    const float* Wa  = (const float*)d_in[10];
    const float* ba  = (const float*)d_in[11];
    const float* Wc  = (const float*)d_in[12];
    const float* bc  = (const float*)d_in[13];
    float* out = (float*)d_out;

    const int N  = in_sizes[0] / 128;
    const int E  = in_sizes[1] / 2;
    const int E2 = E + N;

    // workspace layout (256B-aligned chunks)
    char* base = (char*)d_ws;
    auto alloc = [&](size_t bytes) -> char* {
        char* p = base; base += (bytes + 255) & ~(size_t)255; return p;
    };
    float* h1o  = (float*)alloc((size_t)N*128*4);
    float* h2   = (float*)alloc((size_t)N*32*4);
    float* as1  = (float*)alloc((size_t)N*4*4);
    float* ad1  = (float*)alloc((size_t)N*4*4);
    float* as2  = (float*)alloc((size_t)N*4);
    float* ad2  = (float*)alloc((size_t)N*4);
    int* deg    = (int*)alloc((size_t)N*4);
    int* tmp    = (int*)alloc((size_t)N*4);
    int* blkSum = (int*)alloc(1024);
    int* blkOff = (int*)alloc(1024);
    int* rs     = (int*)alloc((size_t)N*4);
    int* re     = (int*)alloc((size_t)N*4);
    int* cur    = (int*)alloc((size_t)N*4);
    int* csr    = (int*)alloc((size_t)E2*4);
    unsigned short* h1b  = (unsigned short*)alloc((size_t)N*128*2);
    unsigned short* h2pb = (unsigned short*)alloc((size_t)N*32*2);

    const int nbN   = (N + 255) / 256;
    const int nbE   = (E2 + 255) / 256;
    const int nbG   = (N + 63) / 64;
    const int nbAgg = (N + 3) / 4;

    hipMemsetAsync(deg, 0, (size_t)N*4, stream);
    k_gemm1<<<nbG, 256, 0, stream>>>(x, W1, a1s, a1d, h1b, as1, ad1, N, ei, E, E2, deg);
    k_scan_local<<<nbN, 256, 0, stream>>>(deg, tmp, blkSum, N);
    k_scan_blk<<<1, 256, 0, stream>>>(blkSum, blkOff, nbN, out + (size_t)32*N, bc);
    k_scan_fix<<<nbN, 256, 0, stream>>>(tmp, blkOff, deg, rs, re, cur, N);
    k_scatter<<<nbE, 256, 0, stream>>>(ei, E, E2, cur, csr);
    k_agg1<<<nbAgg, 256, 0, stream>>>(rs, re, csr, as1, ad1, h1b, b1, h1o, N);
    k_gemm2<<<nbG, 256, 0, stream>>>(h1o, W2, a2s, a2d, h2pb, as2, ad2, N);
    k_agg2<<<nbAgg, 256, 0, stream>>>(rs, re, csr, as2, ad2, h2pb, b2, h2, N);
    k_head<<<nbN, 256, 0, stream>>>(h2, Wa, ba, Wc, N, out);
}

// Round 4
// 309.497 us; speedup vs baseline: 1.4970x; 1.0257x over previous
//
#include <hip/hip_runtime.h>
#include <math.h>

// GAT actor-critic forward on MI355X.
// bf16-MFMA GEMMs (A staged LDS, B pre-transposed bf16), CSR built per-call
// (hist fused into gemm1 + scan + scatter), wave-per-node chunk-16 softmax
// aggregation with bf16 payloads, fp32 accumulation everywhere.

typedef __attribute__((ext_vector_type(8))) short short8;
typedef __attribute__((ext_vector_type(4))) float floatx4;

__device__ __forceinline__ float leaky02(float e){ return e > 0.f ? e : 0.2f*e; }

// bf16 helpers (RNE)
__device__ __forceinline__ unsigned short f2bf(float f){
    union { float f; unsigned int i; } v; v.f = f;
    unsigned int r = v.i + 0x7fffu + ((v.i >> 16) & 1u);
    return (unsigned short)(r >> 16);
}
__device__ __forceinline__ float bfx(unsigned int g){
    union { unsigned int i; float f; } v; v.i = g << 16; return v.f;
}
__device__ __forceinline__ float bfy(unsigned int g){
    union { unsigned int i; float f; } v; v.i = g & 0xffff0000u; return v.f;
}
__device__ __forceinline__ float bf1(unsigned short u){
    union { unsigned int i; float f; } v; v.i = ((unsigned int)u) << 16; return v.f;
}

// ---------------- prep: transpose+convert weights to bf16 [n][k] ----------------
__global__ void k_prep(const float* __restrict__ W1, const float* __restrict__ W2,
                       unsigned short* __restrict__ w1t, unsigned short* __restrict__ w2t)
{
    int tid = threadIdx.x;
    for (int i = tid; i < 128*128; i += 256){
        int nn = i >> 7, k = i & 127;
        w1t[i] = f2bf(W1[k*128 + nn]);
    }
    for (int i = tid; i < 32*128; i += 256){
        int nn = i >> 7, k = i & 127;
        w2t[i] = f2bf(W2[k*32 + nn]);
    }
}

// ---------------- gemm1 (+ fused dst-degree histogram): h1b = bf16(x @ W1) ----------------
__global__ __launch_bounds__(256) void k_gemm1(const float* __restrict__ x,
        const unsigned short* __restrict__ w1t,
        const float* __restrict__ aS, const float* __restrict__ aD,
        unsigned short* __restrict__ h1b, float* __restrict__ pAS, float* __restrict__ pAD, int n,
        const int* __restrict__ ei, int e, int e2, int* __restrict__ deg)
{
    __shared__ unsigned short As[64*136];   // 17.4 KB  [row][k] padded
    __shared__ unsigned short Bs[128*136];  // 34.8 KB  [n][k]  padded
    const int tid  = threadIdx.x;
    const int brow = blockIdx.x*64;

    // fused histogram: fire-and-forget atomics hidden under the GEMM
    {
        int g = blockIdx.x*256 + tid;
        int stride = gridDim.x*256;
        for (; g < e2; g += stride){
            int d = (g < e) ? ei[(size_t)e + g] : (g - e);
            atomicAdd(&deg[d], 1);
        }
    }

    // stage A: x fp32 -> bf16 LDS
    {
        int row = tid >> 2, cb = (tid & 3)*32;
        bool ok = brow + row < n;
        #pragma unroll
        for (int i=0;i<8;i++){
            float4 v = ok ? *(const float4*)&x[(size_t)(brow+row)*128 + cb + i*4]
                          : make_float4(0.f,0.f,0.f,0.f);
            ushort4 b = make_ushort4(f2bf(v.x),f2bf(v.y),f2bf(v.z),f2bf(v.w));
            *(ushort4*)&As[row*136 + cb + i*4] = b;
        }
    }
    // stage B: w1t bf16 [128][128] -> LDS
    {
        int nn = tid >> 1, kb = (tid & 1)*64;
        #pragma unroll
        for (int i=0;i<8;i++)
            *(uint4*)&Bs[nn*136 + kb + i*8] = *(const uint4*)&w1t[nn*128 + kb + i*8];
    }
    __syncthreads();

    const int wv = tid >> 6, lane = tid & 63;
    const int m = lane & 15, quad = lane >> 4;
    floatx4 acc[8];
    #pragma unroll
    for (int i=0;i<8;i++) acc[i] = (floatx4){0.f,0.f,0.f,0.f};

    #pragma unroll
    for (int kc=0; kc<4; kc++){
        int k0 = kc*32 + quad*8;
        short8 a = *(const short8*)&As[(wv*16+m)*136 + k0];
        #pragma unroll
        for (int ct=0; ct<8; ct++){
            short8 b = *(const short8*)&Bs[(ct*16+m)*136 + k0];
            acc[ct] = __builtin_amdgcn_mfma_f32_16x16x32_bf16(a, b, acc[ct], 0,0,0);
        }
    }
    __syncthreads();   // done reading As

    // repack C (bf16) into As as [64][128]
    #pragma unroll
    for (int ct=0; ct<8; ct++){
        #pragma unroll
        for (int r=0;r<4;r++){
            int row = wv*16 + quad*4 + r;
            As[row*128 + ct*16 + m] = f2bf(acc[ct][r]);
        }
    }
    __syncthreads();

    // coalesced global writes + per-(row,head) attention dots
    {
        int row = tid >> 2, hd = tid & 3;
        int grow = brow + row;
        if (grow < n){
            float ps=0.f, pd=0.f;
            #pragma unroll
            for (int i=0;i<4;i++){
                uint4 u = *(const uint4*)&As[row*128 + hd*32 + i*8];
                *(uint4*)&h1b[(size_t)grow*128 + hd*32 + i*8] = u;
                unsigned int uw[4] = {u.x,u.y,u.z,u.w};
                #pragma unroll
                for (int j=0;j<4;j++){
                    float c0 = bfx(uw[j]), c1 = bfy(uw[j]);
                    int cc = hd*32 + i*8 + j*2;
                    ps += c0*aS[cc] + c1*aS[cc+1];
                    pd += c0*aD[cc] + c1*aD[cc+1];
                }
            }
            pAS[grow*4+hd] = ps;
            pAD[grow*4+hd] = pd;
        }
    }
}

// ---------------- 3-kernel exclusive scan over deg -> row_start/row_end/cursor ----------------
__global__ void k_scan_local(const int* __restrict__ deg, int* __restrict__ tmp,
                             int* __restrict__ blkSum, int n)
{
    __shared__ int sb[256];
    int tid = threadIdx.x;
    int i = blockIdx.x*256 + tid;
    int v = (i < n) ? deg[i] : 0;
    sb[tid] = v; __syncthreads();
    for (int off=1; off<256; off<<=1){
        int t = (tid >= off) ? sb[tid-off] : 0;
        __syncthreads();
        if (tid >= off) sb[tid] += t;
        __syncthreads();
    }
    if (i < n) tmp[i] = sb[tid];
    if (tid == 255) blkSum[blockIdx.x] = sb[255];
}

__global__ void k_scan_blk(const int* __restrict__ bs, int* __restrict__ bo, int nb,
                           float* __restrict__ out_val, const float* __restrict__ bc)
{
    __shared__ int sb[256];
    int tid = threadIdx.x;
    if (tid == 0) *out_val = bc[0];
    int v = (tid < nb) ? bs[tid] : 0;
    sb[tid] = v; __syncthreads();
    for (int off=1; off<256; off<<=1){
        int t = (tid >= off) ? sb[tid-off] : 0;
        __syncthreads();
        if (tid >= off) sb[tid] += t;
        __syncthreads();
    }
    if (tid < nb) bo[tid] = sb[tid] - v;
}

__global__ void k_scan_fix(const int* __restrict__ tmp, const int* __restrict__ bo,
                           const int* __restrict__ deg, int* __restrict__ rs,
                           int* __restrict__ re, int* __restrict__ cur, int n)
{
    int i = blockIdx.x*blockDim.x + threadIdx.x;
    if (i < n){
        int G = tmp[i] + bo[i >> 8];
        int d = deg[i];
        rs[i]  = G - d;
        cur[i] = G - d;
        re[i]  = G;
    }
}

// ---------------- scatter edges into CSR (src lists grouped by dst) ----------------
__global__ void k_scatter(const int* __restrict__ ei, int e, int e2,
                          int* __restrict__ cur, int* __restrict__ csr)
{
    int g = blockIdx.x*blockDim.x + threadIdx.x;
    if (g < e2){
        int s, d;
        if (g < e){ s = ei[g]; d = ei[(size_t)e + g]; }
        else      { s = g - e; d = g - e; }
        int p = atomicAdd(&cur[d], 1);
        csr[p] = s;
    }
}

// ---------------- layer-1 aggregation: chunk-16, lane-parallel exp, 16-deep gather ----------------
__global__ __launch_bounds__(256) void k_agg1(const int* __restrict__ rs, const int* __restrict__ re,
        const int* __restrict__ csr, const float* __restrict__ as1, const float* __restrict__ ad1,
        const unsigned short* __restrict__ h1b, const float* __restrict__ b1,
        unsigned short* __restrict__ h1ob, int n)
{
    const int lane = threadIdx.x & 63;
    const int node = blockIdx.x*4 + (threadIdx.x >> 6);
    if (node >= n) return;
    const int h   = lane >> 4;
    const int f   = lane*2;
    const int j16 = lane & 15;
    const int grp = lane & 48;
    const float adv = ad1[node*4 + h];
    const int start = rs[node], end = re[node];
    const unsigned int* hp = (const unsigned int*)h1b + (f >> 1);  // index s*64

    float den = 0.f, ax = 0.f, ay = 0.f;
    int i0 = start;

    for (; i0 + 16 <= end; i0 += 16){
        int sj = csr[i0 + j16];
        float e = __expf(leaky02(as1[sj*4 + h] + adv));
        den += e;
        #pragma unroll
        for (int j = 0; j < 16; j++){
            float ej = __shfl(e,  grp + j, 64);
            int   s2 = __shfl(sj, grp + j, 64);
            unsigned int g = hp[s2*64];
            ax += ej*bfx(g); ay += ej*bfy(g);
        }
    }
    int c = end - i0;
    if (c > 0){
        int jj = (j16 < c) ? j16 : (c-1);
        int sj = csr[i0 + jj];
        float e = __expf(leaky02(as1[sj*4 + h] + adv));
        if (j16 < c) den += e;
        for (int j = 0; j < c; j += 4){
            #pragma unroll
            for (int u = 0; u < 4; u++){
                int je = j + u;
                int jc = (je < c) ? je : (c-1);
                float ej = __shfl(e,  grp + jc, 64);
                int   s2 = __shfl(sj, grp + jc, 64);
                ej = (je < c) ? ej : 0.f;
                unsigned int g = hp[s2*64];
                ax += ej*bfx(g); ay += ej*bfy(g);
            }
        }
    }
    den += __shfl_xor(den, 1, 64);
    den += __shfl_xor(den, 2, 64);
    den += __shfl_xor(den, 4, 64);
    den += __shfl_xor(den, 8, 64);

    float ox = ax/den + b1[f];
    float oy = ay/den + b1[f+1];
    ox = ox > 0.f ? ox : expm1f(ox);
    oy = oy > 0.f ? oy : expm1f(oy);
    unsigned int pk = (unsigned int)f2bf(ox) | ((unsigned int)f2bf(oy) << 16);
    *(unsigned int*)&h1ob[(size_t)node*128 + f] = pk;
}

// ---------------- gemm2 (MFMA): h2pb = bf16(h1ob @ W2); fused a_s/a_d ----------------
__global__ __launch_bounds__(256) void k_gemm2(const unsigned short* __restrict__ h1ob,
        const unsigned short* __restrict__ w2t,
        const float* __restrict__ aS, const float* __restrict__ aD,
        unsigned short* __restrict__ h2pb, float* __restrict__ pAS, float* __restrict__ pAD, int n)
{
    __shared__ unsigned short As[64*136];   // 17.4 KB
    __shared__ unsigned short Bs[32*136];   // 8.7 KB
    const int tid  = threadIdx.x;
    const int brow = blockIdx.x*64;

    {   // stage A (already bf16)
        int row = tid >> 2, cb = (tid & 3)*32;
        bool ok = brow + row < n;
        #pragma unroll
        for (int i=0;i<4;i++){
            uint4 v = ok ? *(const uint4*)&h1ob[(size_t)(brow+row)*128 + cb + i*8]
                         : make_uint4(0,0,0,0);
            *(uint4*)&As[row*136 + cb + i*8] = v;
        }
    }
    {   // stage B: w2t [32][128]
        int nn = tid >> 3, kb = (tid & 7)*16;
        *(uint4*)&Bs[nn*136 + kb]     = *(const uint4*)&w2t[nn*128 + kb];
        *(uint4*)&Bs[nn*136 + kb + 8] = *(const uint4*)&w2t[nn*128 + kb + 8];
    }
    __syncthreads();

    const int wv = tid >> 6, lane = tid & 63;
    const int m = lane & 15, quad = lane >> 4;
    floatx4 acc[2];
    acc[0] = (floatx4){0.f,0.f,0.f,0.f};
    acc[1] = (floatx4){0.f,0.f,0.f,0.f};

    #pragma unroll
    for (int kc=0; kc<4; kc++){
        int k0 = kc*32 + quad*8;
        short8 a = *(const short8*)&As[(wv*16+m)*136 + k0];
        #pragma unroll
        for (int ct=0; ct<2; ct++){
            short8 b = *(const short8*)&Bs[(ct*16+m)*136 + k0];
            acc[ct] = __builtin_amdgcn_mfma_f32_16x16x32_bf16(a, b, acc[ct], 0,0,0);
        }
    }
    __syncthreads();

    #pragma unroll
    for (int ct=0; ct<2; ct++){
        #pragma unroll
        for (int r=0;r<4;r++){
            int row = wv*16 + quad*4 + r;
            As[row*32 + ct*16 + m] = f2bf(acc[ct][r]);
        }
    }
    __syncthreads();

    if (tid < 64){
        int grow = brow + tid;
        if (grow < n){
            float ps=0.f, pd=0.f;
            #pragma unroll
            for (int i=0;i<4;i++){
                uint4 u = *(const uint4*)&As[tid*32 + i*8];
                *(uint4*)&h2pb[(size_t)grow*32 + i*8] = u;
                unsigned int uw[4] = {u.x,u.y,u.z,u.w};
                #pragma unroll
                for (int j=0;j<4;j++){
                    float c0 = bfx(uw[j]), c1 = bfy(uw[j]);
                    int cc = i*8 + j*2;
                    ps += c0*aS[cc] + c1*aS[cc+1];
                    pd += c0*aD[cc] + c1*aD[cc+1];
                }
            }
            pAS[grow] = ps;
            pAD[grow] = pd;
        }
    }
}

// ---------------- layer-2 aggregation: chunk-16, halves split payload edges ----------------
__global__ __launch_bounds__(256) void k_agg2(const int* __restrict__ rs, const int* __restrict__ re,
        const int* __restrict__ csr, const float* __restrict__ as2, const float* __restrict__ ad2,
        const unsigned short* __restrict__ h2pb, const float* __restrict__ b2,
        float* __restrict__ out, int n)
{
    const int lane = threadIdx.x & 63;
    const int node = blockIdx.x*4 + (threadIdx.x >> 6);
    if (node >= n) return;
    const int f    = lane & 31;
    const int half = lane >> 5;
    const int j16  = lane & 15;
    const int grp  = lane & 48;
    const float adv = ad2[node];
    const int start = rs[node], end = re[node];
    const unsigned short* hp = h2pb + f;

    float den = 0.f, acc = 0.f;
    int i0 = start;

    for (; i0 + 16 <= end; i0 += 16){
        int sj = csr[i0 + j16];
        float e = __expf(leaky02(as2[sj] + adv));
        den += e;
        #pragma unroll
        for (int jj = 0; jj < 8; jj++){
            int j = 2*jj + half;
            float ej = __shfl(e,  grp + j, 64);
            int   s2 = __shfl(sj, grp + j, 64);
            acc += ej * bf1(hp[s2*32]);
        }
    }
    int c = end - i0;
    if (c > 0){
        int jj = (j16 < c) ? j16 : (c-1);
        int sj = csr[i0 + jj];
        float e = __expf(leaky02(as2[sj] + adv));
        if (j16 < c) den += e;
        for (int j = half; j < c; j += 8){
            #pragma unroll
            for (int u = 0; u < 4; u++){
                int je = j + 2*u;
                int jc = (je < c) ? je : (c-1);
                float ej = __shfl(e,  grp + (jc & 15), 64);
                int   s2 = __shfl(sj, grp + (jc & 15), 64);
                ej = (je < c) ? ej : 0.f;
                acc += ej * bf1(hp[s2*32]);
            }
        }
    }
    den += __shfl_xor(den, 1, 64);
    den += __shfl_xor(den, 2, 64);
    den += __shfl_xor(den, 4, 64);
    den += __shfl_xor(den, 8, 64);
    acc += __shfl_xor(acc, 32, 64);

    if (half == 0){
        float o = acc/den + b2[f];
        o = o > 0.f ? o : expm1f(o);
        out[(size_t)node*32 + f] = o;
    }
}

// ---------------- heads: logits[A,N] (transposed store) + value mean ----------------
__global__ __launch_bounds__(256) void k_head(const float* __restrict__ h2, const float* __restrict__ Wa,
        const float* __restrict__ ba, const float* __restrict__ Wc, int n, float* __restrict__ out)
{
    __shared__ float WaS[1024];
    __shared__ float baS[32], WcS[32];
    int tid = threadIdx.x;
    *(float4*)&WaS[tid*4] = *(const float4*)&Wa[tid*4];
    if (tid < 32){ baS[tid] = ba[tid]; WcS[tid] = Wc[tid]; }
    __syncthreads();

    int nidx = blockIdx.x*256 + tid;
    bool act = nidx < n;
    float hv[32];
    #pragma unroll
    for (int j=0;j<8;j++){
        float4 v = act ? *(const float4*)&h2[(size_t)nidx*32 + j*4] : make_float4(0.f,0.f,0.f,0.f);
        hv[j*4+0]=v.x; hv[j*4+1]=v.y; hv[j*4+2]=v.z; hv[j*4+3]=v.w;
    }
    #pragma unroll
    for (int a=0;a<32;a++){
        float acc = baS[a];
        #pragma unroll
        for (int c=0;c<32;c++) acc += hv[c]*WaS[c*32+a];
        if (act) out[(size_t)a*n + nidx] = acc;
    }
    float v = 0.f;
    #pragma unroll
    for (int c=0;c<32;c++) v += hv[c]*WcS[c];
    #pragma unroll
    for (int msk=1; msk<64; msk<<=1) v += __shfl_xor(v, msk, 64);
    if ((tid & 63) == 0) atomicAdd(&out[(size_t)32*n], v*(1.0f/n));
}

extern "C" void kernel_launch(void* const* d_in, const int* in_sizes, int n_in,
                              void* d_out, int out_size, void* d_ws, size_t ws_size,
                              hipStream_t stream)
{
    const float* x   = (const float*)d_in[0];
    const int*   ei  = (const int*)d_in[1];
    const float* W1  = (const float*)d_in[2];
    const float* a1s = (const float*)d_in[3];
    const float* a1d = (const float*)d_in[4];
    const float* b1  = (const float*)d_in[5];
    const float* W2  = (const float*)d_in[6];
    const float* a2s = (const float*)d_in[7];
    const float* a2d = (const float*)d_in[8];
    const float* b2  = (const float*)d_in[9];
    const float* Wa  = (const float*)d_in[10];
    const float* ba  = (const float*)d_in[11];
    const float* Wc  = (const float*)d_in[12];
    const float* bc  = (const float*)d_in[13];
    float* out = (float*)d_out;

    const int N  = in_sizes[0] / 128;
    const int E  = in_sizes[1] / 2;
    const int E2 = E + N;

    // workspace layout (256B-aligned chunks)
    char* base = (char*)d_ws;
    auto alloc = [&](size_t bytes) -> char* {
        char* p = base; base += (bytes + 255) & ~(size_t)255; return p;
    };
    float* h2   = (float*)alloc((size_t)N*32*4);
    float* as1  = (float*)alloc((size_t)N*4*4);
    float* ad1  = (float*)alloc((size_t)N*4*4);
    float* as2  = (float*)alloc((size_t)N*4);
    float* ad2  = (float*)alloc((size_t)N*4);
    int* deg    = (int*)alloc((size_t)N*4);
    int* tmp    = (int*)alloc((size_t)N*4);
    int* blkSum = (int*)alloc(1024);
    int* blkOff = (int*)alloc(1024);
    int* rs     = (int*)alloc((size_t)N*4);
    int* re     = (int*)alloc((size_t)N*4);
    int* cur    = (int*)alloc((size_t)N*4);
    int* csr    = (int*)alloc((size_t)E2*4);
    unsigned short* h1b  = (unsigned short*)alloc((size_t)N*128*2);
    unsigned short* h1ob = (unsigned short*)alloc((size_t)N*128*2);
    unsigned short* h2pb = (unsigned short*)alloc((size_t)N*32*2);
    unsigned short* w1t  = (unsigned short*)alloc(128*128*2);
    unsigned short* w2t  = (unsigned short*)alloc(32*128*2);

    const int nbN   = (N + 255) / 256;
    const int nbE   = (E2 + 255) / 256;
    const int nbG   = (N + 63) / 64;
    const int nbAgg = (N + 3) / 4;

    hipMemsetAsync(deg, 0, (size_t)N*4, stream);
    k_prep<<<1, 256, 0, stream>>>(W1, W2, w1t, w2t);
    k_gemm1<<<nbG, 256, 0, stream>>>(x, w1t, a1s, a1d, h1b, as1, ad1, N, ei, E, E2, deg);
    k_scan_local<<<nbN, 256, 0, stream>>>(deg, tmp, blkSum, N);
    k_scan_blk<<<1, 256, 0, stream>>>(blkSum, blkOff, nbN, out + (size_t)32*N, bc);
    k_scan_fix<<<nbN, 256, 0, stream>>>(tmp, blkOff, deg, rs, re, cur, N);
    k_scatter<<<nbE, 256, 0, stream>>>(ei, E, E2, cur, csr);
    k_agg1<<<nbAgg, 256, 0, stream>>>(rs, re, csr, as1, ad1, h1b, b1, h1ob, N);
    k_gemm2<<<nbG, 256, 0, stream>>>(h1ob, w2t, a2s, a2d, h2pb, as2, ad2, N);
    k_agg2<<<nbAgg, 256, 0, stream>>>(rs, re, csr, as2, ad2, h2pb, b2, h2, N);
    k_head<<<nbN, 256, 0, stream>>>(h2, Wa, ba, Wc, N, out);
}